// Round 2
// baseline (16548.085 us; speedup 1.0000x reference)
//
#include <hip/hip_runtime.h>
#include <cstdio>
#include <cstdint>

#define TT    20
#define BATCH 512
#define HID   1024
#define G4    4096
#define BT    (BATCH * TT)   // 10240
#define NCLS  200

__device__ __forceinline__ float sigf(float x) { return 1.0f / (1.0f + __expf(-x)); }

// C[M,N] = A[M,K] @ W[N,K]^T + b1 + b2   (row-major, b1/b2 optional)
// 64x64 tile, BK=16, 256 threads, 4x4 per thread.
__launch_bounds__(256)
__global__ void gemm_bias_kernel(const float* __restrict__ A, const float* __restrict__ W,
                                 const float* __restrict__ b1, const float* __restrict__ b2,
                                 float* __restrict__ C, int M, int N, int K)
{
    __shared__ float As[16][68];
    __shared__ float Ws[16][68];
    const int tid = threadIdx.x;
    const int tx = tid & 15, ty = tid >> 4;
    const int m0 = blockIdx.x * 64;
    const int n0 = blockIdx.y * 64;
    const int lr = tid >> 2;          // 0..63: tile row loaded by this thread
    const int lk = (tid & 3) << 2;    // 0,4,8,12: k offset (float4)
    const int mload = m0 + lr;
    const int nload = n0 + lr;
    const bool mok = (mload < M);
    const bool nok = (nload < N);
    const float* Arow = A + (size_t)mload * K + lk;
    const float* Wrow = W + (size_t)nload * K + lk;
    float acc[4][4] = {};

    for (int k0 = 0; k0 < K; k0 += 16) {
        float4 av = make_float4(0.f, 0.f, 0.f, 0.f);
        float4 wv = make_float4(0.f, 0.f, 0.f, 0.f);
        if (mok) av = *(const float4*)(Arow + k0);
        if (nok) wv = *(const float4*)(Wrow + k0);
        As[lk + 0][lr] = av.x; As[lk + 1][lr] = av.y; As[lk + 2][lr] = av.z; As[lk + 3][lr] = av.w;
        Ws[lk + 0][lr] = wv.x; Ws[lk + 1][lr] = wv.y; Ws[lk + 2][lr] = wv.z; Ws[lk + 3][lr] = wv.w;
        __syncthreads();
#pragma unroll
        for (int k = 0; k < 16; ++k) {
            const float4 a = *(const float4*)&As[k][ty << 2];
            const float4 w = *(const float4*)&Ws[k][tx << 2];
            const float a4[4] = {a.x, a.y, a.z, a.w};
            const float w4[4] = {w.x, w.y, w.z, w.w};
#pragma unroll
            for (int i = 0; i < 4; ++i)
#pragma unroll
                for (int j = 0; j < 4; ++j)
                    acc[i][j] = fmaf(a4[i], w4[j], acc[i][j]);
        }
        __syncthreads();
    }

#pragma unroll
    for (int i = 0; i < 4; ++i) {
        const int m = m0 + (ty << 2) + i;
        if (m >= M) continue;
#pragma unroll
        for (int j = 0; j < 4; ++j) {
            const int n = n0 + (tx << 2) + j;
            if (n >= N) continue;
            float v = acc[i][j];
            if (b1) v += b1[n];
            if (b2) v += b2[n];
            C[(size_t)m * N + n] = v;
        }
    }
}

struct StepArgs {
    const float* Whh[2];
    const float* G[2];     // precomputed x@Wih^T + bih + bhh, (BT, 4096), row = b*TT + t
    const float* hin[2];
    float* hout[2];
    float* c[2];
    int t[2];
};

// Per timestep, 2 LSTMs of one stream (gridDim.z). h@Whh^T fused with the cell update.
// Block: 64 batch rows x 16 j-cols x 4 gates. Col c in [0,64): j = j0 + (c>>2), gate = c&3.
__launch_bounds__(256)
__global__ void lstm_step_kernel(StepArgs args)
{
    const int l = blockIdx.z;
    const float* __restrict__ Whh = args.Whh[l];
    const float* __restrict__ hin = args.hin[l];
    const int tid = threadIdx.x;
    const int tx = tid & 15, ty = tid >> 4;
    const int m0 = blockIdx.x * 64;   // batch tile
    const int j0 = blockIdx.y * 16;   // hidden-unit tile
    __shared__ float As[16][68];
    __shared__ float Ws[16][68];
    const int lr = tid >> 2;
    const int lk = (tid & 3) << 2;
    // weight row for tile col lr: gate = lr&3, j = j0 + (lr>>2)
    const int wrow = ((lr & 3) << 10) + j0 + (lr >> 2);
    const float* Arow = hin + (size_t)(m0 + lr) * HID + lk;
    const float* Wrow = Whh + (size_t)wrow * HID + lk;
    float acc[4][4] = {};

    for (int k0 = 0; k0 < HID; k0 += 16) {
        const float4 av = *(const float4*)(Arow + k0);
        const float4 wv = *(const float4*)(Wrow + k0);
        As[lk + 0][lr] = av.x; As[lk + 1][lr] = av.y; As[lk + 2][lr] = av.z; As[lk + 3][lr] = av.w;
        Ws[lk + 0][lr] = wv.x; Ws[lk + 1][lr] = wv.y; Ws[lk + 2][lr] = wv.z; Ws[lk + 3][lr] = wv.w;
        __syncthreads();
#pragma unroll
        for (int k = 0; k < 16; ++k) {
            const float4 a = *(const float4*)&As[k][ty << 2];
            const float4 w = *(const float4*)&Ws[k][tx << 2];
            const float a4[4] = {a.x, a.y, a.z, a.w};
            const float w4[4] = {w.x, w.y, w.z, w.w};
#pragma unroll
            for (int i = 0; i < 4; ++i)
#pragma unroll
                for (int j = 0; j < 4; ++j)
                    acc[i][j] = fmaf(a4[i], w4[j], acc[i][j]);
        }
        __syncthreads();
    }

    const int t = args.t[l];
    const float* __restrict__ Gt = args.G[l];
    float* __restrict__ cb = args.c[l];
    float* __restrict__ ho = args.hout[l];
    const int j = j0 + tx;   // thread's cols c=tx*4..tx*4+3 -> same j, gates 0..3
#pragma unroll
    for (int i = 0; i < 4; ++i) {
        const int b = m0 + (ty << 2) + i;
        const float* g = Gt + (size_t)(b * TT + t) * G4 + j;
        const float ig = sigf(acc[i][0] + g[0]);
        const float fg = sigf(acc[i][1] + g[1024]);
        const float gv = tanhf(acc[i][2] + g[2048]);
        const float ov = sigf(acc[i][3] + g[3072]);
        const size_t idx = (size_t)b * HID + j;
        const float cn = fg * cb[idx] + ig * gv;
        cb[idx] = cn;
        ho[idx] = ov * tanhf(cn);
    }
}

// fused[b, n] = prod over streams of concat(h_fwd, h_rev); h finals laid out [l][b][j],
// l = stream*2 + dir (0=audio_fwd, 1=audio_rev, 2=resnet_fwd, 3=resnet_rev, 4=c3d_fwd, 5=c3d_rev)
__global__ void fuse_mul_kernel(const float* __restrict__ hfin, float* __restrict__ fused)
{
    const int idx = blockIdx.x * blockDim.x + threadIdx.x;
    if (idx >= BATCH * 2 * HID) return;
    const int b = idx >> 11;       // / 2048
    const int n = idx & 2047;
    const int half = n >> 10;      // 0 = fwd lstms, 1 = rev lstms
    const int j = n & 1023;
    const size_t o = (size_t)b * HID + j;
    const size_t S = (size_t)BATCH * HID;
    fused[idx] = hfin[(size_t)(0 + half) * S + o] *
                 hfin[(size_t)(2 + half) * S + o] *
                 hfin[(size_t)(4 + half) * S + o];
}

extern "C" void kernel_launch(void* const* d_in, const int* in_sizes, int n_in,
                              void* d_out, int out_size, void* d_ws, size_t ws_size,
                              hipStream_t stream)
{
    const float* resnet   = (const float*)d_in[0];
    const float* c3d      = (const float*)d_in[1];
    const float* audio    = (const float*)d_in[2];
    const float* W_audio  = (const float*)d_in[3];
    const float* b_audio  = (const float*)d_in[4];
    const float* W_resnet = (const float*)d_in[5];
    const float* b_resnet = (const float*)d_in[6];
    const float* W_c3d    = (const float*)d_in[7];
    const float* b_c3d    = (const float*)d_in[8];
    const float* Wih[6]; const float* Whh[6]; const float* bih[6]; const float* bhh[6];
    for (int l = 0; l < 6; ++l) {
        Wih[l] = (const float*)d_in[9 + 4 * l];
        Whh[l] = (const float*)d_in[10 + 4 * l];
        bih[l] = (const float*)d_in[11 + 4 * l];
        bhh[l] = (const float*)d_in[12 + 4 * l];
    }
    const float* W_out = (const float*)d_in[33];
    const float* b_out = (const float*)d_in[34];
    float* out = (float*)d_out;

    // workspace layout (floats):
    const size_t szProj = (size_t)3 * BT * HID;        // 126 MB
    const size_t szG    = (size_t)2 * BT * G4;         // 336 MB (reused per stream)
    const size_t szHC   = (size_t)2 * BATCH * HID;     // per ping-pong buffer (2 lstms)
    const size_t szHfin = (size_t)6 * BATCH * HID;
    const size_t szFuse = (size_t)BATCH * 2 * HID;
    const size_t need = (szProj + szG + 3 * szHC + szHfin + szFuse) * sizeof(float);
    if (ws_size < need) {
        fprintf(stderr, "kernel_launch: ws_size %zu < needed %zu\n", ws_size, need);
        return;
    }
    float* w     = (float*)d_ws;
    float* proj  = w;                 // [3][BT][HID]
    float* G     = proj + szProj;     // [2][BT][G4]
    float* hb0   = G + szG;           // [2][BATCH][HID]
    float* hb1   = hb0 + szHC;
    float* cb    = hb1 + szHC;
    float* hfin  = cb + szHC;         // [6][BATCH][HID]
    float* fused = hfin + szHfin;     // [BATCH][2*HID]

    const dim3 blk(256);

    // 1. input projections (proj order: 0=audio, 1=resnet, 2=c3d to match lstm pairs)
    {
        const dim3 g(BT / 64, HID / 64);
        gemm_bias_kernel<<<g, blk, 0, stream>>>(audio,  W_audio,  b_audio,  nullptr, proj + 0 * (size_t)BT * HID, BT, HID, 128);
        gemm_bias_kernel<<<g, blk, 0, stream>>>(resnet, W_resnet, b_resnet, nullptr, proj + 1 * (size_t)BT * HID, BT, HID, 2048);
        gemm_bias_kernel<<<g, blk, 0, stream>>>(c3d,    W_c3d,    b_c3d,    nullptr, proj + 2 * (size_t)BT * HID, BT, HID, 4096);
    }

    // 2. per stream: hoisted input-side GEMMs for fwd+rev, then 20 recurrence steps
    for (int st = 0; st < 3; ++st) {
        for (int d = 0; d < 2; ++d) {
            const int l = st * 2 + d;
            const dim3 g(BT / 64, G4 / 64);
            gemm_bias_kernel<<<g, blk, 0, stream>>>(proj + (size_t)st * BT * HID, Wih[l],
                                                    bih[l], bhh[l], G + (size_t)d * BT * G4,
                                                    BT, G4, HID);
        }

        hipMemsetAsync(hb0, 0, szHC * sizeof(float), stream);
        hipMemsetAsync(cb,  0, szHC * sizeof(float), stream);
        for (int s = 0; s < TT; ++s) {
            StepArgs a;
            float* hin  = (s & 1) ? hb1 : hb0;
            float* hout = (s & 1) ? hb0 : hb1;
            for (int d = 0; d < 2; ++d) {
                const int l = st * 2 + d;
                a.Whh[d]  = Whh[l];
                a.G[d]    = G + (size_t)d * BT * G4;
                a.hin[d]  = hin + (size_t)d * BATCH * HID;
                a.hout[d] = (s == TT - 1) ? (hfin + (size_t)l * BATCH * HID)
                                          : (hout + (size_t)d * BATCH * HID);
                a.c[d]    = cb + (size_t)d * BATCH * HID;
                a.t[d]    = d ? (TT - 1 - s) : s;
            }
            lstm_step_kernel<<<dim3(BATCH / 64, HID / 16, 2), blk, 0, stream>>>(a);
        }
    }

    // 3. fused elementwise product of the three bidirectional finals
    fuse_mul_kernel<<<dim3((BATCH * 2 * HID) / 256), blk, 0, stream>>>(hfin, fused);

    // 4. classifier
    gemm_bias_kernel<<<dim3(BATCH / 64, (NCLS + 63) / 64), blk, 0, stream>>>(fused, W_out, b_out, nullptr, out, BATCH, NCLS, 2 * HID);
}

// Round 3
// 7124.070 us; speedup vs baseline: 2.3228x; 2.3228x over previous
//
#include <hip/hip_runtime.h>
#include <cstdio>
#include <cstdint>

#define TT    20
#define BATCH 512
#define HID   1024
#define G4    4096
#define BT    (BATCH * TT)   // 10240
#define NCLS  200

typedef unsigned short u16;
typedef __attribute__((ext_vector_type(8))) short short8;   // 8 bf16 (4 VGPRs)
typedef __attribute__((ext_vector_type(4))) float f32x4;

__device__ __forceinline__ float sigf(float x) { return 1.0f / (1.0f + __expf(-x)); }

__device__ __forceinline__ u16 f2bf(float x) {
    unsigned u = __float_as_uint(x);
    u += 0x7FFFu + ((u >> 16) & 1u);           // RNE
    return (u16)(u >> 16);
}
__device__ __forceinline__ float bf2f(u16 b) { return __uint_as_float(((unsigned)b) << 16); }
__device__ __forceinline__ void split2(float x, u16& h, u16& l) {
    h = f2bf(x);
    l = f2bf(x - bf2f(h));   // residual is exact in fp32
}

// elementwise fp32 -> (hi, lo) bf16 split
__global__ void split_kernel(const float* __restrict__ x, u16* __restrict__ hi,
                             u16* __restrict__ lo, int n)
{
    for (int i = blockIdx.x * blockDim.x + threadIdx.x; i < n; i += gridDim.x * blockDim.x) {
        u16 h, l; split2(x[i], h, l);
        hi[i] = h; lo[i] = l;
    }
}

// ---------------------------------------------------------------------------
// bf16x3 MFMA GEMM: C[M,N] = A[M,K] @ W[N,K]^T + b1 + b2
// Tile 128x128, BK=32, 256 threads = 4 waves (2x2 quadrants of 64x64).
// A: fp32 (split on stage) if !ASPLIT, else pre-split (Ah, Al).
// W: always pre-split (Wh, Wl).
// Output: fp32 (Cf) or pre-split pair (Ch, Cl) if EMIT.
// Requires M%128==0, N%128==0, K%32==0.
// ---------------------------------------------------------------------------
template<bool ASPLIT, bool EMIT>
__launch_bounds__(256)
__global__ void mfma_gemm(const float* __restrict__ Af,
                          const u16* __restrict__ Ah, const u16* __restrict__ Al,
                          const u16* __restrict__ Wh, const u16* __restrict__ Wl,
                          const float* __restrict__ b1, const float* __restrict__ b2,
                          float* __restrict__ Cf, u16* __restrict__ Ch, u16* __restrict__ Cl,
                          int M, int N, int K)
{
    __shared__ u16 sAh[4][128][8]; __shared__ u16 sAl[4][128][8];
    __shared__ u16 sWh[4][128][8]; __shared__ u16 sWl[4][128][8];
    const int tid = threadIdx.x, lane = tid & 63, w = tid >> 6;
    const int wr = w >> 1, wc = w & 1;
    const int m0 = blockIdx.x * 128, n0 = blockIdx.y * 128;
    const int r = tid & 127;
    const bool stA = tid < 128;

    const float* fa = Af ? Af + (size_t)(m0 + r) * K : nullptr;
    const u16*   ha = Ah ? Ah + (size_t)(m0 + r) * K : nullptr;
    const u16*   la = Al ? Al + (size_t)(m0 + r) * K : nullptr;
    const u16*   hw = Wh + (size_t)(n0 + r) * K;
    const u16*   lw = Wl + (size_t)(n0 + r) * K;

    f32x4 acc[4][4];
#pragma unroll
    for (int i = 0; i < 4; ++i)
#pragma unroll
        for (int j = 0; j < 4; ++j) acc[i][j] = f32x4{0.f, 0.f, 0.f, 0.f};

    for (int k0 = 0; k0 < K; k0 += 32) {
        if (stA) {
            if (ASPLIT) {
#pragma unroll
                for (int kb = 0; kb < 4; ++kb) {
                    *(uint4*)&sAh[kb][r][0] = *(const uint4*)(ha + k0 + kb * 8);
                    *(uint4*)&sAl[kb][r][0] = *(const uint4*)(la + k0 + kb * 8);
                }
            } else {
#pragma unroll
                for (int kb = 0; kb < 4; ++kb) {
                    const float4 x0 = *(const float4*)(fa + k0 + kb * 8);
                    const float4 x1 = *(const float4*)(fa + k0 + kb * 8 + 4);
                    u16 hb[8], lb[8];
                    split2(x0.x, hb[0], lb[0]); split2(x0.y, hb[1], lb[1]);
                    split2(x0.z, hb[2], lb[2]); split2(x0.w, hb[3], lb[3]);
                    split2(x1.x, hb[4], lb[4]); split2(x1.y, hb[5], lb[5]);
                    split2(x1.z, hb[6], lb[6]); split2(x1.w, hb[7], lb[7]);
                    *(uint4*)&sAh[kb][r][0] = *(uint4*)hb;
                    *(uint4*)&sAl[kb][r][0] = *(uint4*)lb;
                }
            }
        } else {
#pragma unroll
            for (int kb = 0; kb < 4; ++kb) {
                *(uint4*)&sWh[kb][r][0] = *(const uint4*)(hw + k0 + kb * 8);
                *(uint4*)&sWl[kb][r][0] = *(const uint4*)(lw + k0 + kb * 8);
            }
        }
        __syncthreads();

        const int kb = lane >> 4, rr = lane & 15;
        short8 Avh[4], Avl[4], Wvh[4], Wvl[4];
#pragma unroll
        for (int i = 0; i < 4; ++i) {
            Avh[i] = *(const short8*)&sAh[kb][wr * 64 + i * 16 + rr][0];
            Avl[i] = *(const short8*)&sAl[kb][wr * 64 + i * 16 + rr][0];
            Wvh[i] = *(const short8*)&sWh[kb][wc * 64 + i * 16 + rr][0];
            Wvl[i] = *(const short8*)&sWl[kb][wc * 64 + i * 16 + rr][0];
        }
#pragma unroll
        for (int i = 0; i < 4; ++i)
#pragma unroll
            for (int j = 0; j < 4; ++j) {
                acc[i][j] = __builtin_amdgcn_mfma_f32_16x16x32_bf16(Avh[i], Wvh[j], acc[i][j], 0, 0, 0);
                acc[i][j] = __builtin_amdgcn_mfma_f32_16x16x32_bf16(Avh[i], Wvl[j], acc[i][j], 0, 0, 0);
                acc[i][j] = __builtin_amdgcn_mfma_f32_16x16x32_bf16(Avl[i], Wvh[j], acc[i][j], 0, 0, 0);
            }
        __syncthreads();
    }

    const int rr = lane & 15, rg = lane >> 4;
#pragma unroll
    for (int j = 0; j < 4; ++j) {
        const int col = n0 + wc * 64 + j * 16 + rr;
        const float bias = (b1 ? b1[col] : 0.f) + (b2 ? b2[col] : 0.f);
#pragma unroll
        for (int i = 0; i < 4; ++i) {
#pragma unroll
            for (int q = 0; q < 4; ++q) {
                const int row = m0 + wr * 64 + i * 16 + rg * 4 + q;
                const float v = acc[i][j][q] + bias;
                if (EMIT) {
                    u16 h, l; split2(v, h, l);
                    Ch[(size_t)row * N + col] = h;
                    Cl[(size_t)row * N + col] = l;
                } else {
                    Cf[(size_t)row * N + col] = v;
                }
            }
        }
    }
}

// ---------------------------------------------------------------------------
// MFMA LSTM step: gates = h_in @ Whh^T (+ G precomputed), then cell update.
// Block: 128 batch rows x 16 hidden units (4 gate-tiles). 4 waves, each
// 32 rows x {16 j x 4 gates}. Lane owns all 4 gates of one (b, j).
// ---------------------------------------------------------------------------
struct Step2 {
    const u16* WhhH[2]; const u16* WhhL[2];
    const float* G[2];
    const u16* hinH[2]; const u16* hinL[2];
    u16* houtH[2]; u16* houtL[2];
    float* c[2]; float* hfin[2];
    int t[2];
};

__launch_bounds__(256)
__global__ void lstm_step_mfma(Step2 a)
{
    const int l = blockIdx.z;
    __shared__ u16 sAh[4][128][8]; __shared__ u16 sAl[4][128][8];
    __shared__ u16 sWh[4][64][8];  __shared__ u16 sWl[4][64][8];
    const int tid = threadIdx.x, lane = tid & 63, w = tid >> 6;
    const int m0 = blockIdx.x * 128;
    const int j0 = blockIdx.y * 16;

    const u16* ha = a.hinH[l] + (size_t)(m0 + (tid & 127)) * HID;
    const u16* la = a.hinL[l] + (size_t)(m0 + (tid & 127)) * HID;
    const int wrr = tid - 128;                       // 0..63 for W stagers
    const int wrow = ((wrr & 63) >> 4) * HID + j0 + (wrr & 15);
    const u16* hw = a.WhhH[l] + (size_t)wrow * HID;
    const u16* lw = a.WhhL[l] + (size_t)wrow * HID;

    f32x4 acc[2][4];
#pragma unroll
    for (int i = 0; i < 2; ++i)
#pragma unroll
        for (int g = 0; g < 4; ++g) acc[i][g] = f32x4{0.f, 0.f, 0.f, 0.f};

    for (int k0 = 0; k0 < HID; k0 += 32) {
        if (tid < 128) {
            const int r = tid;
#pragma unroll
            for (int kb = 0; kb < 4; ++kb) {
                *(uint4*)&sAh[kb][r][0] = *(const uint4*)(ha + k0 + kb * 8);
                *(uint4*)&sAl[kb][r][0] = *(const uint4*)(la + k0 + kb * 8);
            }
        } else if (tid < 192) {
            const int r = tid - 128;
#pragma unroll
            for (int kb = 0; kb < 4; ++kb) {
                *(uint4*)&sWh[kb][r][0] = *(const uint4*)(hw + k0 + kb * 8);
                *(uint4*)&sWl[kb][r][0] = *(const uint4*)(lw + k0 + kb * 8);
            }
        }
        __syncthreads();

        const int kb = lane >> 4, rr = lane & 15;
        short8 Avh[2], Avl[2], Wvh[4], Wvl[4];
#pragma unroll
        for (int i = 0; i < 2; ++i) {
            Avh[i] = *(const short8*)&sAh[kb][w * 32 + i * 16 + rr][0];
            Avl[i] = *(const short8*)&sAl[kb][w * 32 + i * 16 + rr][0];
        }
#pragma unroll
        for (int g = 0; g < 4; ++g) {
            Wvh[g] = *(const short8*)&sWh[kb][g * 16 + rr][0];
            Wvl[g] = *(const short8*)&sWl[kb][g * 16 + rr][0];
        }
#pragma unroll
        for (int i = 0; i < 2; ++i)
#pragma unroll
            for (int g = 0; g < 4; ++g) {
                acc[i][g] = __builtin_amdgcn_mfma_f32_16x16x32_bf16(Avh[i], Wvh[g], acc[i][g], 0, 0, 0);
                acc[i][g] = __builtin_amdgcn_mfma_f32_16x16x32_bf16(Avh[i], Wvl[g], acc[i][g], 0, 0, 0);
                acc[i][g] = __builtin_amdgcn_mfma_f32_16x16x32_bf16(Avl[i], Wvh[g], acc[i][g], 0, 0, 0);
            }
        __syncthreads();
    }

    const int rr = lane & 15, rg = lane >> 4;
    const int j = j0 + rr;
    const int t = a.t[l];
    const float* __restrict__ G = a.G[l];
    float* __restrict__ cb = a.c[l];
    float* __restrict__ hf = a.hfin[l];
    u16* __restrict__ hoH = a.houtH[l];
    u16* __restrict__ hoL = a.houtL[l];
#pragma unroll
    for (int i = 0; i < 2; ++i) {
#pragma unroll
        for (int q = 0; q < 4; ++q) {
            const int b = m0 + w * 32 + i * 16 + rg * 4 + q;
            const float* gp = G + ((size_t)b * TT + t) * G4 + j;
            const float pi = acc[i][0][q] + gp[0];
            const float pf = acc[i][1][q] + gp[1024];
            const float pg = acc[i][2][q] + gp[2048];
            const float po = acc[i][3][q] + gp[3072];
            const size_t idx = (size_t)b * HID + j;
            const float cn = sigf(pf) * cb[idx] + sigf(pi) * tanhf(pg);
            cb[idx] = cn;
            const float h = sigf(po) * tanhf(cn);
            hf[idx] = h;
            u16 hh, hl; split2(h, hh, hl);
            hoH[idx] = hh; hoL[idx] = hl;
        }
    }
}

// fused[b, n] = prod over streams of concat(h_fwd, h_rev); hfin layout [l][b][j]
__global__ void fuse_mul_kernel(const float* __restrict__ hfin, float* __restrict__ fused)
{
    const int idx = blockIdx.x * blockDim.x + threadIdx.x;
    if (idx >= BATCH * 2 * HID) return;
    const int b = idx >> 11;
    const int n = idx & 2047;
    const int half = n >> 10;
    const int j = n & 1023;
    const size_t o = (size_t)b * HID + j;
    const size_t S = (size_t)BATCH * HID;
    fused[idx] = hfin[(size_t)(0 + half) * S + o] *
                 hfin[(size_t)(2 + half) * S + o] *
                 hfin[(size_t)(4 + half) * S + o];
}

// fp32 vector GEMM for the small classifier (N=200): C = A@W^T + b
__launch_bounds__(256)
__global__ void gemm_bias_kernel(const float* __restrict__ A, const float* __restrict__ W,
                                 const float* __restrict__ b1,
                                 float* __restrict__ C, int M, int N, int K)
{
    __shared__ float As[16][68];
    __shared__ float Ws[16][68];
    const int tid = threadIdx.x;
    const int tx = tid & 15, ty = tid >> 4;
    const int m0 = blockIdx.x * 64;
    const int n0 = blockIdx.y * 64;
    const int lr = tid >> 2;
    const int lk = (tid & 3) << 2;
    const bool mok = (m0 + lr < M);
    const bool nok = (n0 + lr < N);
    const float* Arow = A + (size_t)(m0 + lr) * K + lk;
    const float* Wrow = W + (size_t)(n0 + lr) * K + lk;
    float acc[4][4] = {};

    for (int k0 = 0; k0 < K; k0 += 16) {
        float4 av = make_float4(0.f, 0.f, 0.f, 0.f);
        float4 wv = make_float4(0.f, 0.f, 0.f, 0.f);
        if (mok) av = *(const float4*)(Arow + k0);
        if (nok) wv = *(const float4*)(Wrow + k0);
        As[lk + 0][lr] = av.x; As[lk + 1][lr] = av.y; As[lk + 2][lr] = av.z; As[lk + 3][lr] = av.w;
        Ws[lk + 0][lr] = wv.x; Ws[lk + 1][lr] = wv.y; Ws[lk + 2][lr] = wv.z; Ws[lk + 3][lr] = wv.w;
        __syncthreads();
#pragma unroll
        for (int k = 0; k < 16; ++k) {
            const float4 a = *(const float4*)&As[k][ty << 2];
            const float4 ww = *(const float4*)&Ws[k][tx << 2];
            const float a4[4] = {a.x, a.y, a.z, a.w};
            const float w4[4] = {ww.x, ww.y, ww.z, ww.w};
#pragma unroll
            for (int i = 0; i < 4; ++i)
#pragma unroll
                for (int j = 0; j < 4; ++j)
                    acc[i][j] = fmaf(a4[i], w4[j], acc[i][j]);
        }
        __syncthreads();
    }

#pragma unroll
    for (int i = 0; i < 4; ++i) {
        const int m = m0 + (ty << 2) + i;
        if (m >= M) continue;
#pragma unroll
        for (int j = 0; j < 4; ++j) {
            const int n = n0 + (tx << 2) + j;
            if (n >= N) continue;
            C[(size_t)m * N + n] = acc[i][j] + (b1 ? b1[n] : 0.f);
        }
    }
}

extern "C" void kernel_launch(void* const* d_in, const int* in_sizes, int n_in,
                              void* d_out, int out_size, void* d_ws, size_t ws_size,
                              hipStream_t stream)
{
    const float* resnet   = (const float*)d_in[0];
    const float* c3d      = (const float*)d_in[1];
    const float* audio    = (const float*)d_in[2];
    const float* W_audio  = (const float*)d_in[3];
    const float* b_audio  = (const float*)d_in[4];
    const float* W_resnet = (const float*)d_in[5];
    const float* b_resnet = (const float*)d_in[6];
    const float* W_c3d    = (const float*)d_in[7];
    const float* b_c3d    = (const float*)d_in[8];
    const float* Wih[6]; const float* Whh[6]; const float* bih[6]; const float* bhh[6];
    for (int l = 0; l < 6; ++l) {
        Wih[l] = (const float*)d_in[9 + 4 * l];
        Whh[l] = (const float*)d_in[10 + 4 * l];
        bih[l] = (const float*)d_in[11 + 4 * l];
        bhh[l] = (const float*)d_in[12 + 4 * l];
    }
    const float* W_out = (const float*)d_in[33];
    const float* b_out = (const float*)d_in[34];
    float* out = (float*)d_out;

    // ---- workspace carve (bytes) ----
    char* p = (char*)d_ws;
    char* pend = p + ws_size;
    auto alloc = [&](size_t bytes) -> void* {
        void* q = p; p += (bytes + 255) & ~(size_t)255; return q;
    };
    const size_t FW = (size_t)1024 * (128 + 2048 + 4096);    // feature weight elems
    u16* fwH  = (u16*)alloc(FW * 2);
    u16* fwL  = (u16*)alloc(FW * 2);
    u16* wihH = (u16*)alloc((size_t)2 * G4 * HID * 2);
    u16* wihL = (u16*)alloc((size_t)2 * G4 * HID * 2);
    u16* whhH = (u16*)alloc((size_t)2 * G4 * HID * 2);
    u16* whhL = (u16*)alloc((size_t)2 * G4 * HID * 2);
    u16* projH = (u16*)alloc((size_t)3 * BT * HID * 2);
    u16* projL = (u16*)alloc((size_t)3 * BT * HID * 2);
    float* G   = (float*)alloc((size_t)2 * BT * G4 * 4);
    u16* hAH = (u16*)alloc((size_t)2 * BATCH * HID * 2);
    u16* hAL = (u16*)alloc((size_t)2 * BATCH * HID * 2);
    u16* hBH = (u16*)alloc((size_t)2 * BATCH * HID * 2);
    u16* hBL = (u16*)alloc((size_t)2 * BATCH * HID * 2);
    float* cb   = (float*)alloc((size_t)2 * BATCH * HID * 4);
    float* hfin = (float*)alloc((size_t)6 * BATCH * HID * 4);
    float* fused = (float*)alloc((size_t)BATCH * 2 * HID * 4);
    if (p > pend) {
        fprintf(stderr, "kernel_launch: ws too small: need %zu have %zu\n",
                (size_t)(p - (char*)d_ws), ws_size);
        return;
    }

    const dim3 blk(256);
    const size_t offA = 0, offR = (size_t)1024 * 128, offC = offR + (size_t)1024 * 2048;

    // 0. split feature weights
    split_kernel<<<dim3(512), blk, 0, stream>>>(W_audio,  fwH + offA, fwL + offA, 1024 * 128);
    split_kernel<<<dim3(2048), blk, 0, stream>>>(W_resnet, fwH + offR, fwL + offR, 1024 * 2048);
    split_kernel<<<dim3(2048), blk, 0, stream>>>(W_c3d,    fwH + offC, fwL + offC, 1024 * 4096);

    // 1. input projections -> bf16 split pair (proj order: 0=audio, 1=resnet, 2=c3d)
    {
        const dim3 g(BT / 128, HID / 128);
        mfma_gemm<false, true><<<g, blk, 0, stream>>>(
            audio, nullptr, nullptr, fwH + offA, fwL + offA, b_audio, nullptr,
            nullptr, projH + 0 * (size_t)BT * HID, projL + 0 * (size_t)BT * HID, BT, HID, 128);
        mfma_gemm<false, true><<<g, blk, 0, stream>>>(
            resnet, nullptr, nullptr, fwH + offR, fwL + offR, b_resnet, nullptr,
            nullptr, projH + 1 * (size_t)BT * HID, projL + 1 * (size_t)BT * HID, BT, HID, 2048);
        mfma_gemm<false, true><<<g, blk, 0, stream>>>(
            c3d, nullptr, nullptr, fwH + offC, fwL + offC, b_c3d, nullptr,
            nullptr, projH + 2 * (size_t)BT * HID, projL + 2 * (size_t)BT * HID, BT, HID, 4096);
    }

    // 2. per stream: weight splits, hoisted G GEMMs, 20 recurrence steps
    for (int st = 0; st < 3; ++st) {
        for (int d = 0; d < 2; ++d) {
            const int l = st * 2 + d;
            const size_t woff = (size_t)d * G4 * HID;
            split_kernel<<<dim3(2048), blk, 0, stream>>>(Wih[l], wihH + woff, wihL + woff, G4 * HID);
            split_kernel<<<dim3(2048), blk, 0, stream>>>(Whh[l], whhH + woff, whhL + woff, G4 * HID);
            mfma_gemm<true, false><<<dim3(BT / 128, G4 / 128), blk, 0, stream>>>(
                nullptr, projH + (size_t)st * BT * HID, projL + (size_t)st * BT * HID,
                wihH + woff, wihL + woff, bih[l], bhh[l],
                G + (size_t)d * BT * G4, nullptr, nullptr, BT, G4, HID);
        }

        hipMemsetAsync(hAH, 0, (size_t)2 * BATCH * HID * 2, stream);
        hipMemsetAsync(hAL, 0, (size_t)2 * BATCH * HID * 2, stream);
        hipMemsetAsync(cb,  0, (size_t)2 * BATCH * HID * 4, stream);

        for (int s = 0; s < TT; ++s) {
            Step2 a;
            u16* inH  = (s & 1) ? hBH : hAH;  u16* inL  = (s & 1) ? hBL : hAL;
            u16* outH = (s & 1) ? hAH : hBH;  u16* outL = (s & 1) ? hAL : hBL;
            for (int d = 0; d < 2; ++d) {
                const int l = st * 2 + d;
                const size_t woff = (size_t)d * G4 * HID;
                const size_t hoff = (size_t)d * BATCH * HID;
                a.WhhH[d] = whhH + woff; a.WhhL[d] = whhL + woff;
                a.G[d]    = G + (size_t)d * BT * G4;
                a.hinH[d] = inH + hoff;  a.hinL[d] = inL + hoff;
                a.houtH[d] = outH + hoff; a.houtL[d] = outL + hoff;
                a.c[d]    = cb + hoff;
                a.hfin[d] = hfin + (size_t)l * BATCH * HID;
                a.t[d]    = d ? (TT - 1 - s) : s;
            }
            lstm_step_mfma<<<dim3(BATCH / 128, HID / 16, 2), blk, 0, stream>>>(a);
        }
    }

    // 3. fused elementwise product
    fuse_mul_kernel<<<dim3((BATCH * 2 * HID) / 256), blk, 0, stream>>>(hfin, fused);

    // 4. classifier (small, fp32 vector path)
    gemm_bias_kernel<<<dim3(BATCH / 64, (NCLS + 63) / 64), blk, 0, stream>>>(
        fused, W_out, b_out, out, BATCH, NCLS, 2 * HID);
}